// Round 1
// baseline (958.332 us; speedup 1.0000x reference)
//
#include <hip/hip_runtime.h>

#define NB 4
#define SEQ 1024
#define NH 32
#define NKV 8
#define HD 64
#define QBLK 32

typedef __attribute__((ext_vector_type(8))) short short8;
typedef __attribute__((ext_vector_type(4))) float f32x4;

__device__ __forceinline__ unsigned short f2bf(float f) {
  union { float f; unsigned u; } x; x.f = f;
  unsigned u = x.u;
  u += 0x7fffu + ((u >> 16) & 1u);   // round-to-nearest-even
  return (unsigned short)(u >> 16);
}

__global__ __launch_bounds__(256, 2) void gqa_kernel(
    const float* __restrict__ Qg, const float* __restrict__ Kg,
    const float* __restrict__ Vg, float* __restrict__ Og) {
  __shared__ unsigned short Plds[QBLK * SEQ];  // 64KB, bf16 P, XOR-swizzled
  __shared__ unsigned short VsT[HD * 64];      // 8KB, V^T chunk [d][k], swizzled
  __shared__ float redmax[QBLK][4];
  __shared__ float redsum[QBLK][4];

  const int tid = threadIdx.x;
  const int lane = tid & 63;
  const int wid = tid >> 6;
  const int li = lane & 15;
  const int g = lane >> 4;

  const int gid = blockIdx.x;
  const int qt = gid & 31;
  const int h = (gid >> 5) & 31;
  const int b = gid >> 10;
  const int hkv = h >> 2;
  const int q0 = qt * QBLK;

  const float* Qp = Qg + ((size_t)b * SEQ) * 2048 + h * 64;
  const float* Kp = Kg + ((size_t)b * SEQ) * 512 + hkv * 64;
  const float* Vp = Vg + ((size_t)b * SEQ) * 512 + hkv * 64;
  float* Outp = Og + ((size_t)b * SEQ) * 2048 + h * 64;
  float* Attnp = Og + (size_t)NB * SEQ * 2048
               + (((size_t)(b * NH + h)) * SEQ + q0) * SEQ;

  char* pb = (char*)&Plds[0];
  char* vb_ = (char*)&VsT[0];

  // ---- Q fragments, scale 1/8 folded in fp32 (exact, power of 2) ----
  short8 aq[2][2];
#pragma unroll
  for (int m = 0; m < 2; ++m)
#pragma unroll
    for (int dh = 0; dh < 2; ++dh) {
      const float* qp = Qp + (size_t)(q0 + m * 16 + li) * 2048 + dh * 32 + g * 8;
      float4 x = *(const float4*)qp;
      float4 y = *(const float4*)(qp + 4);
      short8 t;
      t[0] = (short)f2bf(x.x * 0.125f); t[1] = (short)f2bf(x.y * 0.125f);
      t[2] = (short)f2bf(x.z * 0.125f); t[3] = (short)f2bf(x.w * 0.125f);
      t[4] = (short)f2bf(y.x * 0.125f); t[5] = (short)f2bf(y.y * 0.125f);
      t[6] = (short)f2bf(y.z * 0.125f); t[7] = (short)f2bf(y.w * 0.125f);
      aq[m][dh] = t;
    }

  // ---- QK^T: wave owns cols [wid*256, wid*256+256) ----
  f32x4 acc[2][16];
  f32x4 zero4 = {0.f, 0.f, 0.f, 0.f};
#pragma unroll
  for (int m = 0; m < 2; ++m)
#pragma unroll
    for (int j = 0; j < 16; ++j) acc[m][j] = zero4;

  const int colbase = wid * 256 + li;
#pragma unroll 4
  for (int j = 0; j < 16; ++j) {
    int col = colbase + j * 16;
    short8 bk[2];
#pragma unroll
    for (int dh = 0; dh < 2; ++dh) {
      const float* kp = Kp + (size_t)col * 512 + dh * 32 + g * 8;
      float4 x = *(const float4*)kp;
      float4 y = *(const float4*)(kp + 4);
      short8 t;
      t[0]=(short)f2bf(x.x); t[1]=(short)f2bf(x.y); t[2]=(short)f2bf(x.z); t[3]=(short)f2bf(x.w);
      t[4]=(short)f2bf(y.x); t[5]=(short)f2bf(y.y); t[6]=(short)f2bf(y.z); t[7]=(short)f2bf(y.w);
      bk[dh] = t;
    }
#pragma unroll
    for (int m = 0; m < 2; ++m) {
      acc[m][j] = __builtin_amdgcn_mfma_f32_16x16x32_bf16(aq[m][0], bk[0], acc[m][j], 0, 0, 0);
      acc[m][j] = __builtin_amdgcn_mfma_f32_16x16x32_bf16(aq[m][1], bk[1], acc[m][j], 0, 0, 0);
    }
  }

  // ---- softmax: C layout row=(lane>>4)*4+r, col=lane&15 ----
#pragma unroll
  for (int m = 0; m < 2; ++m)
#pragma unroll
    for (int r = 0; r < 4; ++r) {
      float mx = -1e30f;
#pragma unroll
      for (int j = 0; j < 16; ++j) mx = fmaxf(mx, acc[m][j][r]);
      mx = fmaxf(mx, __shfl_xor(mx, 1));
      mx = fmaxf(mx, __shfl_xor(mx, 2));
      mx = fmaxf(mx, __shfl_xor(mx, 4));
      mx = fmaxf(mx, __shfl_xor(mx, 8));
      if (li == 0) redmax[m * 16 + g * 4 + r][wid] = mx;
    }
  __syncthreads();

#pragma unroll
  for (int m = 0; m < 2; ++m)
#pragma unroll
    for (int r = 0; r < 4; ++r) {
      int row = m * 16 + g * 4 + r;
      float mx = fmaxf(fmaxf(redmax[row][0], redmax[row][1]),
                       fmaxf(redmax[row][2], redmax[row][3]));
      float s = 0.f;
#pragma unroll
      for (int j = 0; j < 16; ++j) {
        float e = __expf(acc[m][j][r] - mx);
        acc[m][j][r] = e;
        s += e;
      }
      s += __shfl_xor(s, 1);
      s += __shfl_xor(s, 2);
      s += __shfl_xor(s, 4);
      s += __shfl_xor(s, 8);
      if (li == 0) redsum[row][wid] = s;
    }
  __syncthreads();

  // ---- normalize; write attn (f32 global) + P (bf16 LDS, swizzled) ----
#pragma unroll
  for (int m = 0; m < 2; ++m)
#pragma unroll
    for (int r = 0; r < 4; ++r) {
      int row = m * 16 + g * 4 + r;
      float L = redsum[row][0] + redsum[row][1] + redsum[row][2] + redsum[row][3];
      float inv = 1.0f / L;
      float* arow = Attnp + (size_t)row * SEQ + colbase;
#pragma unroll
      for (int j = 0; j < 16; ++j) {
        float p = acc[m][j][r] * inv;
        arow[j * 16] = p;
        int col = colbase + j * 16;
        *(unsigned short*)(pb + (((row << 11) + (col << 1)) ^ ((row & 7) << 4))) = f2bf(p);
      }
    }
  __syncthreads();

  // ---- PV: wave -> out tile rows m_o*16..+15, cols nb_..nb_+31, full K ----
  const int m_o = wid >> 1;
  const int nb_ = (wid & 1) * 32;
  f32x4 acc0 = zero4, acc1 = zero4;

  for (int c = 0; c < 16; ++c) {
    // stage V chunk transposed: VsT[d][k_local], 64 k-rows
#pragma unroll
    for (int p = 0; p < 4; ++p) {
      int kl = p * 16 + (tid >> 4);
      int d0 = (tid & 15) * 4;
      float4 vv = *(const float4*)(Vp + (size_t)(c * 64 + kl) * 512 + d0);
      float vals[4] = {vv.x, vv.y, vv.z, vv.w};
#pragma unroll
      for (int i = 0; i < 4; ++i) {
        int d = d0 + i;
        *(unsigned short*)(vb_ + (((d << 7) + (kl << 1)) ^ (((d >> 1) & 7) << 4))) = f2bf(vals[i]);
      }
    }
    __syncthreads();

#pragma unroll
    for (int kt = 0; kt < 2; ++kt) {
      int colk = c * 64 + kt * 32 + g * 8;
      int prow = m_o * 16 + li;
      short8 pa = *(const short8*)(pb + (((prow << 11) + (colk << 1)) ^ ((prow & 7) << 4)));
#pragma unroll
      for (int nn = 0; nn < 2; ++nn) {
        int d = nb_ + nn * 16 + li;
        int kk = kt * 32 + g * 8;
        short8 vbf = *(const short8*)(vb_ + (((d << 7) + (kk << 1)) ^ (((d >> 1) & 7) << 4)));
        if (nn == 0) acc0 = __builtin_amdgcn_mfma_f32_16x16x32_bf16(pa, vbf, acc0, 0, 0, 0);
        else         acc1 = __builtin_amdgcn_mfma_f32_16x16x32_bf16(pa, vbf, acc1, 0, 0, 0);
      }
    }
    __syncthreads();
  }

  // ---- epilogue: out[q0+m_o*16+g*4+r][nb_ + nn*16 + li] ----
#pragma unroll
  for (int r = 0; r < 4; ++r) {
    int row = q0 + m_o * 16 + g * 4 + r;
    Outp[(size_t)row * 2048 + nb_ + li] = acc0[r];
    Outp[(size_t)row * 2048 + nb_ + 16 + li] = acc1[r];
  }
}

extern "C" void kernel_launch(void* const* d_in, const int* in_sizes, int n_in,
                              void* d_out, int out_size, void* d_ws, size_t ws_size,
                              hipStream_t stream) {
  const float* q = (const float*)d_in[0];
  const float* k = (const float*)d_in[1];
  const float* v = (const float*)d_in[2];
  float* o = (float*)d_out;
  dim3 grid(NB * NH * (SEQ / QBLK));  // 4096
  dim3 block(256);
  hipLaunchKernelGGL(gqa_kernel, grid, block, 0, stream, q, k, v, o);
}